// Round 16
// baseline (40.694 us; speedup 1.0000x reference)
//
#include <hip/hip_runtime.h>

#define NT 256

typedef float f32x2 __attribute__((ext_vector_type(2)));
typedef float f32x4 __attribute__((ext_vector_type(4)));

#if defined(__has_builtin)
#if __has_builtin(__builtin_amdgcn_exp2f)
#define EXP2F __builtin_amdgcn_exp2f
#else
#define EXP2F exp2f
#endif
#else
#define EXP2F exp2f
#endif

__device__ __forceinline__ f32x2 bc2(float w) {
    f32x2 r; r.x = w; r.y = w; return r;
}
__device__ __forceinline__ f32x2 pfma(f32x2 a, f32x2 b, f32x2 c) {
    return __builtin_elementwise_fma(a, b, c);
}

// ws layout (floats):
//   [0..119]   W1' = C*W1          (C = -log2(e))
//   [120..143] b1' = C*b1
//   [144..239] W2' = C*W2
//   [240..263] b2' = C*b2
//   [264..287] fw[6][4]  (fc3(+fc4) folded per-branch 4-vec)
//   [288..291] fb[4]     (folded output biases)
#define WS_W1 0
#define WS_B1 120
#define WS_W2 144
#define WS_B2 240
#define WS_FW 264
#define WS_FB 288

__global__ void mlp6_prefold(const float* __restrict__ W1, const float* __restrict__ b1,
                             const float* __restrict__ W2, const float* __restrict__ b2,
                             const float* __restrict__ W3_2, const float* __restrict__ b3_2,
                             const float* __restrict__ W3_1, const float* __restrict__ b3_1,
                             const float* __restrict__ W4, const float* __restrict__ b4,
                             float* __restrict__ ws)
{
    const float C = -1.442695040888963f;
    int t = threadIdx.x;
    if (t < 120) {
        ws[WS_W1 + t] = C * W1[t];
    } else if (t < 144) {
        ws[WS_B1 + (t - 120)] = C * b1[t - 120];
    } else if (t < 240) {
        ws[WS_W2 + (t - 144)] = C * W2[t - 144];
    } else if (t < 264) {
        ws[WS_B2 + (t - 240)] = C * b2[t - 240];
    } else if (t < 288) {
        // W3_2 flat [4][2][4] rows j=0..3 <-> branches {0,1,4,5}; W4 flat [2][1][4];
        // W3_1 flat [2][1][4].
        int q = t - 264, k = q >> 2, h = q & 3;
        float v;
        if (k == 0)      v = W4[0]*W3_2[h]      + W4[1]*W3_2[4 + h];
        else if (k == 1) v = W4[4]*W3_2[8 + h]  + W4[5]*W3_2[12 + h];
        else if (k == 2) v = W3_1[h];
        else if (k == 3) v = W3_1[4 + h];
        else if (k == 4) v = W4[2]*W3_2[16 + h] + W4[3]*W3_2[20 + h];
        else             v = W4[6]*W3_2[24 + h] + W4[7]*W3_2[28 + h];
        ws[WS_FW + q] = v;
    } else if (t < 292) {
        int j = t - 288;
        float v;
        if (j == 0)      v = b3_1[0];
        else if (j == 1) v = b3_1[1];
        else if (j == 2) v = W4[0]*b3_2[0] + W4[1]*b3_2[1] + W4[2]*b3_2[4] + W4[3]*b3_2[5] + b4[0];
        else             v = W4[4]*b3_2[2] + W4[5]*b3_2[3] + W4[6]*b3_2[6] + W4[7]*b3_2[7] + b4[1];
        ws[WS_FB + j] = v;
    }
}

// per-element sigmoid, preactivation PRE-SCALED by -log2(e):
// sigma = rcp(1 + exp2(v)). 3-op dependent chain, no cross-element coupling.
__device__ __forceinline__ f32x2 sig2(f32x2 v) {
    f32x2 e;
    e.x = EXP2F(v.x);
    e.y = EXP2F(v.y);
    f32x2 d = e + bc2(1.0f);
    f32x2 r;
    r.x = __builtin_amdgcn_rcpf(d.x);
    r.y = __builtin_amdgcn_rcpf(d.y);
    return r;
}

__global__ __launch_bounds__(NT, 3)
void mlp6_fused(const float* __restrict__ xl,
                const float* __restrict__ yl,
                const float* __restrict__ xr,
                const float* __restrict__ ws,
                float* __restrict__ out, int nq)
{
    // ---- bijective XCD-chunked swizzle (8 XCDs): each XCD works a
    // contiguous 1/8 slab of the arrays -> L2/L3 locality, HBM row coherence.
    int nwg = gridDim.x;
    int q8  = nwg >> 3, r8 = nwg & 7;
    int bid = blockIdx.x;
    int xcd = bid & 7, idx = bid >> 3;
    int swz = (xcd < r8 ? xcd * (q8 + 1) : r8 * (q8 + 1) + (xcd - r8) * q8) + idx;

    int gq = swz * NT + threadIdx.x;
    if (gq >= nq) gq = nq - 1;                 // clamped dup-writes are identical

    // ---- load 2 samples x 5 feats per array as 5x dwordx2 (8B-aligned) ----
    f32x2 LA[5], LB[5], LC[5];
    {
        const f32x2* x2 = (const f32x2*)xl + (long long)gq * 5;
        const f32x2* y2 = (const f32x2*)yl + (long long)gq * 5;
        const f32x2* c2 = (const f32x2*)xr + (long long)gq * 5;
        #pragma unroll
        for (int q = 0; q < 5; q++) LA[q] = x2[q];
        #pragma unroll
        for (int q = 0; q < 5; q++) LB[q] = y2[q];
        #pragma unroll
        for (int q = 0; q < 5; q++) LC[q] = c2[q];
    }
    // repack to per-feature sample-pairs
    f32x2 xp[5], yp[5], cp[5];
    xp[0].x = LA[0].x; xp[0].y = LA[2].y;
    xp[1].x = LA[0].y; xp[1].y = LA[3].x;
    xp[2].x = LA[1].x; xp[2].y = LA[3].y;
    xp[3].x = LA[1].y; xp[3].y = LA[4].x;
    xp[4].x = LA[2].x; xp[4].y = LA[4].y;
    yp[0].x = LB[0].x; yp[0].y = LB[2].y;
    yp[1].x = LB[0].y; yp[1].y = LB[3].x;
    yp[2].x = LB[1].x; yp[2].y = LB[3].y;
    yp[3].x = LB[1].y; yp[3].y = LB[4].x;
    yp[4].x = LB[2].x; yp[4].y = LB[4].y;
    cp[0].x = LC[0].x; cp[0].y = LC[2].y;
    cp[1].x = LC[0].y; cp[1].y = LC[3].x;
    cp[2].x = LC[1].x; cp[2].y = LC[3].y;
    cp[3].x = LC[1].y; cp[3].y = LC[4].x;
    cp[4].x = LC[2].x; cp[4].y = LC[4].y;

    const float* wW1 = ws + WS_W1;
    const float* wb1 = ws + WS_B1;
    const float* wW2 = ws + WS_W2;
    const float* wb2 = ws + WS_B2;
    const float* wfw = ws + WS_FW;
    const float* wfb = ws + WS_FB;

    f32x2 o0 = bc2(wfb[0]), o1 = bc2(wfb[1]), o2 = bc2(wfb[2]), o3 = bc2(wfb[3]);

    // ---- TWO branches processed as interleaved independent chains ----
    auto pair2 = [&](int kA, const f32x2 (&inA)[5], f32x2& oA,
                     int kB, const f32x2 (&inB)[5], f32x2& oB) {
        f32x2 hA[4], hB[4];
        #pragma unroll
        for (int hh = 0; hh < 4; hh++) {
            f32x2 aA = pfma(inA[0], bc2(wW1[kA*20 + hh*5]), bc2(wb1[kA*4 + hh]));
            f32x2 aB = pfma(inB[0], bc2(wW1[kB*20 + hh*5]), bc2(wb1[kB*4 + hh]));
            #pragma unroll
            for (int q = 1; q < 5; q++) {
                aA = pfma(inA[q], bc2(wW1[kA*20 + hh*5 + q]), aA);
                aB = pfma(inB[q], bc2(wW1[kB*20 + hh*5 + q]), aB);
            }
            hA[hh] = sig2(aA);
            hB[hh] = sig2(aB);
        }
        f32x2 cA[4], cB[4];
        #pragma unroll
        for (int g = 0; g < 4; g++) {
            f32x2 aA = pfma(hA[0], bc2(wW2[kA*16 + g*4]), bc2(wb2[kA*4 + g]));
            f32x2 aB = pfma(hB[0], bc2(wW2[kB*16 + g*4]), bc2(wb2[kB*4 + g]));
            #pragma unroll
            for (int q = 1; q < 4; q++) {
                aA = pfma(hA[q], bc2(wW2[kA*16 + g*4 + q]), aA);
                aB = pfma(hB[q], bc2(wW2[kB*16 + g*4 + q]), aB);
            }
            cA[g] = sig2(aA);
            cB[g] = sig2(aB);
        }
        #pragma unroll
        for (int g = 0; g < 4; g++) {
            oA = pfma(cA[g], bc2(wfw[kA*4 + g]), oA);
            oB = pfma(cB[g], bc2(wfw[kB*4 + g]), oB);
        }
    };

    // X = stack([xl, yl, xr, yl, xl, yl]); slots: br2->o0, br3->o1,
    // {br0,br4}->o2, {br1,br5}->o3. Pairs chosen with disjoint inputs/outputs.
    pair2(0, xp, o2, 1, yp, o3);
    pair2(4, xp, o2, 3, yp, o1);
    pair2(5, yp, o3, 2, cp, o0);

    f32x4 r0, r1;
    r0.x = o0.x; r0.y = o1.x; r0.z = o2.x; r0.w = o3.x;
    r1.x = o0.y; r1.y = o1.y; r1.z = o2.y; r1.w = o3.y;
    // nontemporal: output is write-once/never-read -> don't evict inputs
    // from L2/L3 (inputs+output ~152 MB vs 256 MB L3).
    f32x4* out4 = (f32x4*)out + (long long)gq * 2;
    __builtin_nontemporal_store(r0, out4);
    __builtin_nontemporal_store(r1, out4 + 1);
}

extern "C" void kernel_launch(void* const* d_in, const int* in_sizes, int n_in,
                              void* d_out, int out_size, void* d_ws, size_t ws_size,
                              hipStream_t stream) {
    const float* xl   = (const float*)d_in[0];
    const float* yl   = (const float*)d_in[1];
    const float* xr   = (const float*)d_in[2];
    // d_in[3] = yr — unused by the reference forward
    const float* W1   = (const float*)d_in[4];
    const float* b1   = (const float*)d_in[5];
    const float* W2   = (const float*)d_in[6];
    const float* b2   = (const float*)d_in[7];
    const float* W3_2 = (const float*)d_in[8];
    const float* b3_2 = (const float*)d_in[9];
    const float* W3_1 = (const float*)d_in[10];
    const float* b3_1 = (const float*)d_in[11];
    const float* W4   = (const float*)d_in[12];
    const float* b4   = (const float*)d_in[13];
    float* out = (float*)d_out;
    float* ws  = (float*)d_ws;

    mlp6_prefold<<<1, 320, 0, stream>>>(
        W1, b1, W2, b2, W3_2, b3_2, W3_1, b3_1, W4, b4, ws);

    int B  = in_sizes[0] / 5;              // 2,000,000 (even)
    int nq = B >> 1;                       // sample pairs
    int blocks = (nq + NT - 1) / NT;
    mlp6_fused<<<blocks, NT, 0, stream>>>(xl, yl, xr, ws, out, nq);
}

// Round 17
// 38.949 us; speedup vs baseline: 1.0448x; 1.0448x over previous
//
#include <hip/hip_runtime.h>

#define NT 256

typedef float f32x2 __attribute__((ext_vector_type(2)));
typedef float f32x4 __attribute__((ext_vector_type(4)));

#if defined(__has_builtin)
#if __has_builtin(__builtin_amdgcn_exp2f)
#define EXP2F __builtin_amdgcn_exp2f
#else
#define EXP2F exp2f
#endif
#else
#define EXP2F exp2f
#endif

__device__ __forceinline__ f32x2 bc2(float w) {
    f32x2 r; r.x = w; r.y = w; return r;
}
__device__ __forceinline__ f32x2 pfma(f32x2 a, f32x2 b, f32x2 c) {
    return __builtin_elementwise_fma(a, b, c);
}

// ws layout (floats):
//   [0..119]   W1' = C*W1          (C = -log2(e))
//   [120..143] b1' = C*b1
//   [144..239] W2' = C*W2
//   [240..263] b2' = C*b2
//   [264..287] fw[6][4]  (fc3(+fc4) folded per-branch 4-vec)
//   [288..291] fb[4]     (folded output biases)
#define WS_W1 0
#define WS_B1 120
#define WS_W2 144
#define WS_B2 240
#define WS_FW 264
#define WS_FB 288

__global__ void mlp6_prefold(const float* __restrict__ W1, const float* __restrict__ b1,
                             const float* __restrict__ W2, const float* __restrict__ b2,
                             const float* __restrict__ W3_2, const float* __restrict__ b3_2,
                             const float* __restrict__ W3_1, const float* __restrict__ b3_1,
                             const float* __restrict__ W4, const float* __restrict__ b4,
                             float* __restrict__ ws)
{
    const float C = -1.442695040888963f;
    int t = threadIdx.x;
    if (t < 120) {
        ws[WS_W1 + t] = C * W1[t];
    } else if (t < 144) {
        ws[WS_B1 + (t - 120)] = C * b1[t - 120];
    } else if (t < 240) {
        ws[WS_W2 + (t - 144)] = C * W2[t - 144];
    } else if (t < 264) {
        ws[WS_B2 + (t - 240)] = C * b2[t - 240];
    } else if (t < 288) {
        // W3_2 flat [4][2][4] rows j=0..3 <-> branches {0,1,4,5}; W4 flat [2][1][4];
        // W3_1 flat [2][1][4].
        int q = t - 264, k = q >> 2, h = q & 3;
        float v;
        if (k == 0)      v = W4[0]*W3_2[h]      + W4[1]*W3_2[4 + h];
        else if (k == 1) v = W4[4]*W3_2[8 + h]  + W4[5]*W3_2[12 + h];
        else if (k == 2) v = W3_1[h];
        else if (k == 3) v = W3_1[4 + h];
        else if (k == 4) v = W4[2]*W3_2[16 + h] + W4[3]*W3_2[20 + h];
        else             v = W4[6]*W3_2[24 + h] + W4[7]*W3_2[28 + h];
        ws[WS_FW + q] = v;
    } else if (t < 292) {
        int j = t - 288;
        float v;
        if (j == 0)      v = b3_1[0];
        else if (j == 1) v = b3_1[1];
        else if (j == 2) v = W4[0]*b3_2[0] + W4[1]*b3_2[1] + W4[2]*b3_2[4] + W4[3]*b3_2[5] + b4[0];
        else             v = W4[4]*b3_2[2] + W4[5]*b3_2[3] + W4[6]*b3_2[6] + W4[7]*b3_2[7] + b4[1];
        ws[WS_FB + j] = v;
    }
}

// per-element sigmoid, preactivation PRE-SCALED by -log2(e):
// sigma = rcp(1 + exp2(v)). 3-op dependent chain.
__device__ __forceinline__ f32x2 sig2(f32x2 v) {
    f32x2 e;
    e.x = EXP2F(v.x);
    e.y = EXP2F(v.y);
    f32x2 d = e + bc2(1.0f);
    f32x2 r;
    r.x = __builtin_amdgcn_rcpf(d.x);
    r.y = __builtin_amdgcn_rcpf(d.y);
    return r;
}

__device__ __forceinline__ void repack5(const f32x2 L[5], f32x2 p[5]) {
    p[0].x = L[0].x; p[0].y = L[2].y;
    p[1].x = L[0].y; p[1].y = L[3].x;
    p[2].x = L[1].x; p[2].y = L[3].y;
    p[3].x = L[1].y; p[3].y = L[4].x;
    p[4].x = L[2].x; p[4].y = L[4].y;
}

__global__ __launch_bounds__(NT, 2)
void mlp6_fused(const float* __restrict__ xl,
                const float* __restrict__ yl,
                const float* __restrict__ xr,
                const float* __restrict__ ws,
                float* __restrict__ out, int nq, int nqh)
{
    int t = blockIdx.x * NT + threadIdx.x;
    if (t >= nqh) t = nqh - 1;                 // clamped dup-writes are identical
    int g0 = t;
    int g1 = t + nqh;
    if (g1 >= nq) g1 = nq - 1;

    const float* wW1 = ws + WS_W1;
    const float* wb1 = ws + WS_B1;
    const float* wW2 = ws + WS_W2;
    const float* wb2 = ws + WS_B2;
    const float* wfw = ws + WS_FW;
    const float* wfb = ws + WS_FB;

    // ---- TWO branches processed as interleaved independent chains ----
    auto pair2 = [&](int kA, const f32x2 (&inA)[5], f32x2& oA,
                     int kB, const f32x2 (&inB)[5], f32x2& oB) {
        f32x2 hA[4], hB[4];
        #pragma unroll
        for (int hh = 0; hh < 4; hh++) {
            f32x2 aA = pfma(inA[0], bc2(wW1[kA*20 + hh*5]), bc2(wb1[kA*4 + hh]));
            f32x2 aB = pfma(inB[0], bc2(wW1[kB*20 + hh*5]), bc2(wb1[kB*4 + hh]));
            #pragma unroll
            for (int q = 1; q < 5; q++) {
                aA = pfma(inA[q], bc2(wW1[kA*20 + hh*5 + q]), aA);
                aB = pfma(inB[q], bc2(wW1[kB*20 + hh*5 + q]), aB);
            }
            hA[hh] = sig2(aA);
            hB[hh] = sig2(aB);
        }
        f32x2 cA[4], cB[4];
        #pragma unroll
        for (int g = 0; g < 4; g++) {
            f32x2 aA = pfma(hA[0], bc2(wW2[kA*16 + g*4]), bc2(wb2[kA*4 + g]));
            f32x2 aB = pfma(hB[0], bc2(wW2[kB*16 + g*4]), bc2(wb2[kB*4 + g]));
            #pragma unroll
            for (int q = 1; q < 4; q++) {
                aA = pfma(hA[q], bc2(wW2[kA*16 + g*4 + q]), aA);
                aB = pfma(hB[q], bc2(wW2[kB*16 + g*4 + q]), aB);
            }
            cA[g] = sig2(aA);
            cB[g] = sig2(aB);
        }
        #pragma unroll
        for (int g = 0; g < 4; g++) {
            oA = pfma(cA[g], bc2(wfw[kA*4 + g]), oA);
            oB = pfma(cB[g], bc2(wfw[kB*4 + g]), oB);
        }
    };

    const f32x2* x0 = (const f32x2*)xl + (long long)g0 * 5;
    const f32x2* y0 = (const f32x2*)yl + (long long)g0 * 5;
    const f32x2* c0 = (const f32x2*)xr + (long long)g0 * 5;
    const f32x2* x1 = (const f32x2*)xl + (long long)g1 * 5;
    const f32x2* y1 = (const f32x2*)yl + (long long)g1 * 5;
    const f32x2* c1 = (const f32x2*)xr + (long long)g1 * 5;

    // ---- pair0 loads (needed now) ----
    f32x2 LA0[5], LB0[5], LC0[5];
    #pragma unroll
    for (int q = 0; q < 5; q++) LA0[q] = x0[q];
    #pragma unroll
    for (int q = 0; q < 5; q++) LB0[q] = y0[q];
    #pragma unroll
    for (int q = 0; q < 5; q++) LC0[q] = c0[q];
    // ---- pair1 xl prefetch: issue-early, used ~1400cy later ----
    f32x2 LA1[5];
    #pragma unroll
    for (int q = 0; q < 5; q++) LA1[q] = x1[q];

    f32x2 xp[5], yp[5], cp[5];
    repack5(LA0, xp);
    repack5(LB0, yp);
    repack5(LC0, cp);

    f32x2 o0 = bc2(wfb[0]), o1 = bc2(wfb[1]), o2 = bc2(wfb[2]), o3 = bc2(wfb[3]);

    // X = stack([xl, yl, xr, yl, xl, yl]); slots: br2->o0, br3->o1,
    // {br0,br4}->o2, {br1,br5}->o3.
    pair2(0, xp, o2, 1, yp, o3);
    // ---- pair1 yl prefetch under compute ----
    f32x2 LB1[5];
    #pragma unroll
    for (int q = 0; q < 5; q++) LB1[q] = y1[q];
    pair2(4, xp, o2, 3, yp, o1);
    // ---- pair1 xr prefetch under compute ----
    f32x2 LC1[5];
    #pragma unroll
    for (int q = 0; q < 5; q++) LC1[q] = c1[q];
    pair2(5, yp, o3, 2, cp, o0);

    {
        f32x4 r0, r1;
        r0.x = o0.x; r0.y = o1.x; r0.z = o2.x; r0.w = o3.x;
        r1.x = o0.y; r1.y = o1.y; r1.z = o2.y; r1.w = o3.y;
        f32x4* o4 = (f32x4*)out + (long long)g0 * 2;
        o4[0] = r0;
        o4[1] = r1;
    }

    // ---- pair1 compute (loads landed long ago) ----
    repack5(LA1, xp);
    repack5(LB1, yp);
    repack5(LC1, cp);

    f32x2 p0 = bc2(wfb[0]), p1 = bc2(wfb[1]), p2 = bc2(wfb[2]), p3 = bc2(wfb[3]);
    pair2(0, xp, p2, 1, yp, p3);
    pair2(4, xp, p2, 3, yp, p1);
    pair2(5, yp, p3, 2, cp, p0);

    {
        f32x4 r0, r1;
        r0.x = p0.x; r0.y = p1.x; r0.z = p2.x; r0.w = p3.x;
        r1.x = p0.y; r1.y = p1.y; r1.z = p2.y; r1.w = p3.y;
        f32x4* o4 = (f32x4*)out + (long long)g1 * 2;
        o4[0] = r0;
        o4[1] = r1;
    }
}

extern "C" void kernel_launch(void* const* d_in, const int* in_sizes, int n_in,
                              void* d_out, int out_size, void* d_ws, size_t ws_size,
                              hipStream_t stream) {
    const float* xl   = (const float*)d_in[0];
    const float* yl   = (const float*)d_in[1];
    const float* xr   = (const float*)d_in[2];
    // d_in[3] = yr — unused by the reference forward
    const float* W1   = (const float*)d_in[4];
    const float* b1   = (const float*)d_in[5];
    const float* W2   = (const float*)d_in[6];
    const float* b2   = (const float*)d_in[7];
    const float* W3_2 = (const float*)d_in[8];
    const float* b3_2 = (const float*)d_in[9];
    const float* W3_1 = (const float*)d_in[10];
    const float* b3_1 = (const float*)d_in[11];
    const float* W4   = (const float*)d_in[12];
    const float* b4   = (const float*)d_in[13];
    float* out = (float*)d_out;
    float* ws  = (float*)d_ws;

    mlp6_prefold<<<1, 320, 0, stream>>>(
        W1, b1, W2, b2, W3_2, b3_2, W3_1, b3_1, W4, b4, ws);

    int B   = in_sizes[0] / 5;             // 2,000,000 (even)
    int nq  = B >> 1;                      // 1,000,000 sample pairs
    int nqh = (nq + 1) >> 1;               // pairs per thread-slot (2 pairs/thread)
    int blocks = (nqh + NT - 1) / NT;
    mlp6_fused<<<blocks, NT, 0, stream>>>(xl, yl, xr, ws, out, nq, nqh);
}